// Round 2
// baseline (226.781 us; speedup 1.0000x reference)
//
#include <hip/hip_runtime.h>

using short8  = __attribute__((ext_vector_type(8))) short;
using short4v = __attribute__((ext_vector_type(4))) short;
using floatx4 = __attribute__((ext_vector_type(4))) float;

#define MFMA_B16(a, b, c) __builtin_amdgcn_mfma_f32_16x16x32_bf16(a, b, c, 0, 0, 0)

__device__ __forceinline__ short f2bf(float f) {
  union { float f; unsigned u; } v; v.f = f;
  unsigned r = v.u + 0x7fffu + ((v.u >> 16) & 1u);
  return (short)(r >> 16);
}
// truncating cast (P>=0; bias cancels between PV numerator and ones-column denom)
__device__ __forceinline__ short f2bf_rtz(float f) {
  union { float f; unsigned u; } v; v.f = f;
  return (short)(v.u >> 16);
}

// async global->LDS, 16B per lane; lds dest = wave-uniform base + lane*16
__device__ __forceinline__ void gload_lds16(const short* g, short* l) {
  __builtin_amdgcn_global_load_lds(
      (const __attribute__((address_space(1))) unsigned int*)g,
      (__attribute__((address_space(3))) unsigned int*)l, 16, 0, 0);
}

// ---------------- prep: cast x -> bf16  +  transpose/cast weights ----------------
__global__ __launch_bounds__(256) void prep(
    const float4* __restrict__ x, short4v* __restrict__ xb,
    const float* __restrict__ w0, const float* __restrict__ w1,
    const float* __restrict__ w2, const float* __restrict__ w3,
    short* __restrict__ wT) {
  __shared__ float tile[32][33];
  int blk = blockIdx.x;
  if (blk < 8192) {
    int i = blk * 256 + threadIdx.x;
    float4 v = x[i];
    short4v o = { f2bf(v.x), f2bf(v.y), f2bf(v.z), f2bf(v.w) };
    xb[i] = o;
  } else {
    int r = blk - 8192;
    int z = r >> 10; r &= 1023;
    const float* w = z == 0 ? w0 : (z == 1 ? w1 : (z == 2 ? w2 : w3));
    short* out = wT + (size_t)z * 1024 * 1024;
    int n0 = (r & 31) * 32, k0 = (r >> 5) * 32;
    int tx = threadIdx.x & 31, ty = threadIdx.x >> 5;
#pragma unroll
    for (int i = 0; i < 4; ++i)
      tile[ty + i * 8][tx] = w[(size_t)(k0 + ty + i * 8) * 1024 + n0 + tx];
    __syncthreads();
#pragma unroll
    for (int i = 0; i < 4; ++i)
      out[(size_t)(n0 + ty + i * 8) * 1024 + k0 + tx] = f2bf(tile[tx][ty + i * 8]);
  }
}

// ---------------- 8-phase-style GEMM core: BM=256, BN=128, BK=64 ----------------
// 512 threads = 8 waves (2 M-rows x 4 N-cols), per-wave 128x32 output.
// 2 phases per K-tile; counted vmcnt(3) at K-tile boundary (never 0 in steady
// state); LDS reads XOR-swizzled (byte ^= (row&7)<<4) with the inverse
// permutation pre-applied to the per-lane GLOBAL source address so the linear
// global_load_lds write lands data at swizzled spots (rule 21).
// Staging units = 64 rows x 64 cols bf16 = 8KB = 512 threads x 16B (1 issue).
// Unit schedule derived from read retirement:
//   A.q0,q2 + B.q0,q1 retire at p0;  A.q1,q3 retire at p1.
//   tile T+2 first-3 {A.q0,A.q2,B.q0} staged at T.p1 (same-parity buf, retired)
//   tile T+2 last-3  {A.q1,A.q3,B.q1} staged at (T+1).p0 (other buf being read)
// -> at T.p1 boundary, outstanding = the 3 just-issued units -> vmcnt(3).
__device__ __forceinline__ void gemm_core_256x128(
    const short* __restrict__ Ag0, const short* __restrict__ Bg0,
    short* As /* [2][16384] */, short* Bs /* [2][8192] */,
    floatx4 (&acc)[8][2]) {
  const int tid = threadIdx.x;
  const int w = tid >> 6, lane = tid & 63, quad = lane >> 4, l16 = lane & 15;
  const int wm = w >> 2, wn = w & 3;
  // staging: thread -> (row-in-unit, source granule) with inverse swizzle
  const int srow = tid >> 3;                       // 0..63
  const int scol = ((tid & 7) ^ (srow & 7)) * 8;   // shorts

  floatx4 zf = {0.f, 0.f, 0.f, 0.f};
#pragma unroll
  for (int i = 0; i < 8; ++i) { acc[i][0] = zf; acc[i][1] = zf; }

  const short* gA = Ag0 + (size_t)srow * 1024 + scol;
  const short* gB = Bg0 + (size_t)srow * 1024 + scol;

  auto stA = [&](int buf, int q, int kt) {
    gload_lds16(gA + (size_t)q * 64 * 1024 + kt * 64,
                As + buf * 16384 + q * 4096 + w * 512);
  };
  auto stB = [&](int buf, int q, int kt) {
    gload_lds16(gB + (size_t)q * 64 * 1024 + kt * 64,
                Bs + buf * 8192 + q * 4096 + w * 512);
  };

  short8 aF[8], bF[4];
  auto ldA = [&](int buf, int mh) {
    const char* base = (const char*)(As + buf * 16384);
#pragma unroll
    for (int m = 0; m < 4; ++m)
#pragma unroll
      for (int kk = 0; kk < 2; ++kk) {
        int row = wm * 128 + mh * 64 + m * 16 + l16;
        int off = row * 128 + kk * 64 + quad * 16;
        off ^= (row & 7) << 4;
        aF[m * 2 + kk] = *(const short8*)(base + off);
      }
  };
  auto ldB = [&](int buf) {
    const char* base = (const char*)(Bs + buf * 8192);
#pragma unroll
    for (int nf = 0; nf < 2; ++nf)
#pragma unroll
      for (int kk = 0; kk < 2; ++kk) {
        int row = wn * 32 + nf * 16 + l16;
        int off = row * 128 + kk * 64 + quad * 16;
        off ^= (row & 7) << 4;
        bF[nf * 2 + kk] = *(const short8*)(base + off);
      }
  };
  auto mm = [&](int mh) {
#pragma unroll
    for (int m = 0; m < 4; ++m)
#pragma unroll
      for (int nf = 0; nf < 2; ++nf)
#pragma unroll
        for (int kk = 0; kk < 2; ++kk)
          acc[mh * 4 + m][nf] =
              MFMA_B16(aF[m * 2 + kk], bF[nf * 2 + kk], acc[mh * 4 + m][nf]);
  };

  // prologue: tile0 all 6 units + tile1 first-3; only tile1's 3 may stay in flight
  stA(0, 0, 0); stA(0, 1, 0); stA(0, 2, 0); stA(0, 3, 0);
  stB(0, 0, 0); stB(0, 1, 0);
  stA(1, 0, 1); stA(1, 2, 1); stB(1, 0, 1);
  asm volatile("s_waitcnt vmcnt(3)" ::: "memory");
  __builtin_amdgcn_s_barrier();

#pragma unroll 2
  for (int t = 0; t < 16; ++t) {
    const int cb = t & 1, nb = cb ^ 1;
    // ---- phase 0 (mh = 0): reads A.q(2*wm) + B; stages tile t+1 last-3 -> other buf
    ldA(cb, 0);
    ldB(cb);
    if (t + 1 < 16) { stA(nb, 1, t + 1); stA(nb, 3, t + 1); stB(nb, 1, t + 1); }
    __builtin_amdgcn_sched_barrier(0);
    __builtin_amdgcn_s_barrier();
    asm volatile("s_waitcnt lgkmcnt(0)" ::: "memory");
    __builtin_amdgcn_sched_barrier(0);
    __builtin_amdgcn_s_setprio(1);
    mm(0);
    __builtin_amdgcn_s_setprio(0);
    __builtin_amdgcn_sched_barrier(0);
    __builtin_amdgcn_s_barrier();
    // ---- phase 1 (mh = 1): reads A.q(2*wm+1); stages tile t+2 first-3 -> this buf
    ldA(cb, 1);
    if (t + 2 < 16) {
      stA(cb, 0, t + 2); stA(cb, 2, t + 2); stB(cb, 0, t + 2);
      asm volatile("s_waitcnt vmcnt(3)" ::: "memory");   // tile t+1 fully landed
    } else {
      asm volatile("s_waitcnt vmcnt(0)" ::: "memory");   // tail drain
    }
    __builtin_amdgcn_sched_barrier(0);
    __builtin_amdgcn_s_barrier();
    asm volatile("s_waitcnt lgkmcnt(0)" ::: "memory");
    __builtin_amdgcn_sched_barrier(0);
    __builtin_amdgcn_s_setprio(1);
    mm(1);
    __builtin_amdgcn_s_setprio(0);
    __builtin_amdgcn_sched_barrier(0);
    __builtin_amdgcn_s_barrier();
  }
}

// ---------------- QKV projection GEMM (fused), 256x128 8-phase-style ----------------
// z=0: Q scaled by log2(e)/8; z=1: K; z=2: V.  All out (B,H,L,D) bf16.
__global__ __launch_bounds__(512, 2) void gemm_qkv(
    const short* __restrict__ xb, const short* __restrict__ wT,
    const float* __restrict__ bq, const float* __restrict__ bk,
    const float* __restrict__ bv, short* __restrict__ qkv) {
  __shared__ __align__(16) short As[2 * 16384];
  __shared__ __align__(16) short Bs[2 * 8192];
  int z = blockIdx.z;
  const short* wt = wT + (size_t)z * 1024 * 1024;
  const float* bias = z == 0 ? bq : (z == 1 ? bk : bv);
  short* out = qkv + (size_t)z * 8192 * 1024;
  int m0 = blockIdx.x * 256, n0 = blockIdx.y * 128;

  floatx4 acc[8][2];
  gemm_core_256x128(xb + (size_t)m0 * 1024, wt + (size_t)n0 * 1024, As, Bs, acc);

  int tid = threadIdx.x, w = tid >> 6, lane = tid & 63, quad = lane >> 4, l16 = lane & 15;
  int wm = w >> 2, wn = w & 3;
  // Q pre-scaled by log2(e)/sqrt(D) so attention can use exp2
  float qs = (z == 0) ? 0.125f * 1.44269504f : 1.0f;
#pragma unroll
  for (int mf = 0; mf < 8; ++mf)
#pragma unroll
    for (int nf = 0; nf < 2; ++nf)
#pragma unroll
      for (int rg = 0; rg < 4; ++rg) {
        int m = m0 + wm * 128 + mf * 16 + quad * 4 + rg;
        int cc = n0 + wn * 32 + nf * 16 + l16;
        float v = (acc[mf][nf][rg] + bias[cc]) * qs;
        int b = m >> 12, l = m & 4095;
        int hh = cc >> 6, d = cc & 63;
        out[((size_t)(b * 16 + hh) * 4096 + l) * 64 + d] = f2bf(v);
      }
}

// ---------------- windowed attention (unchanged) ----------------
__global__ __launch_bounds__(256) void attn_kern(const short* __restrict__ qkv,
                                                 short* __restrict__ attnb) {
  const int L = 4096, H = 16;
  int n = blockIdx.x, h = blockIdx.y, b = blockIdx.z;
  const size_t hs = (size_t)L * 64;
  const short* Qp = qkv + (size_t)(b * H + h) * hs;
  const short* Kp = qkv + (size_t)8192 * 1024 + (size_t)(b * H + h) * hs;
  const short* Vp = qkv + (size_t)2 * 8192 * 1024 + (size_t)(b * H + h) * hs;

  __shared__ __align__(16) short kt[128][72];
  __shared__ __align__(16) short vt[64][136];   // vt[d][key]
  __shared__ __align__(16) short pl[4][32][136];

  int tid = threadIdx.x, w = tid >> 6, lane = tid & 63, quad = lane >> 4, l16 = lane & 15;

  // ones B-fragment (col 0 of a 16-col tile = 1): sums P rows via MFMA
  short8 onesf;
  {
    short ov = (l16 == 0) ? (short)0x3F80 : (short)0;
#pragma unroll
    for (int j = 0; j < 8; ++j) onesf[j] = ov;
  }

  // preload Q A-fragments (Q pre-scaled by log2e/8)
  short8 qf[2][2];
#pragma unroll
  for (int rt = 0; rt < 2; ++rt)
#pragma unroll
    for (int ks = 0; ks < 2; ++ks)
      qf[rt][ks] = *(const short8*)(Qp + (size_t)(n * 128 + w * 32 + rt * 16 + l16) * 64 + ks * 32 + quad * 8);

  floatx4 zf = {0.f, 0.f, 0.f, 0.f};
  floatx4 o[2][4];
  floatx4 osum[2];
#pragma unroll
  for (int i = 0; i < 2; ++i) {
    osum[i] = zf;
#pragma unroll
    for (int j = 0; j < 4; ++j) o[i][j] = zf;
  }

#pragma unroll
  for (int c = 0; c < 3; ++c) {
    int bk = n - 1 + c;
    bool inr = (c == 1) || (c == 0 ? (n > 0) : (n < 31));
    __syncthreads();   // prior chunk's kt/vt readers done before restage
    if (inr) {
      const short* kc_ = Kp + (size_t)bk * 128 * 64;
      int kr = tid >> 2, ksg = (tid & 3) * 16;
#pragma unroll
      for (int p = 0; p < 2; ++p) {
        int r2 = p * 64 + kr;
        *(short8*)(&kt[r2][ksg])     = *(const short8*)(kc_ + r2 * 64 + ksg);
        *(short8*)(&kt[r2][ksg + 8]) = *(const short8*)(kc_ + r2 * 64 + ksg + 8);
      }
      // V transpose-in-LDS: thread -> key (tid&31), d-seg (tid>>5)*8
      const short* vc_ = Vp + (size_t)bk * 128 * 64;
      int vkey = tid & 31, vsg = (tid >> 5) * 8;
#pragma unroll
      for (int p = 0; p < 4; ++p) {
        int r2 = p * 32 + vkey;
        short8 vv = *(const short8*)(vc_ + r2 * 64 + vsg);
#pragma unroll
        for (int j = 0; j < 8; ++j) vt[vsg + j][r2] = vv[j];
      }
    } else {
      short8 z8 = {0, 0, 0, 0, 0, 0, 0, 0};
      int kr = tid >> 2, ksg = (tid & 3) * 16;
#pragma unroll
      for (int p = 0; p < 2; ++p) {
        int r2 = p * 64 + kr;
        *(short8*)(&kt[r2][ksg])     = z8;
        *(short8*)(&kt[r2][ksg + 8]) = z8;
      }
      int vr = tid >> 2, vsg2 = (tid & 3) * 32;
#pragma unroll
      for (int q2 = 0; q2 < 4; ++q2) *(short8*)(&vt[vr][vsg2 + q2 * 8]) = z8;
    }
    __syncthreads();

    // S = Q K^T; skip fully-masked 16-col tiles (wave-uniform: wrt = w*2+rt)
    floatx4 s[2][8];
#pragma unroll
    for (int rt = 0; rt < 2; ++rt)
#pragma unroll
      for (int ct = 0; ct < 8; ++ct) s[rt][ct] = zf;
#pragma unroll
    for (int ct = 0; ct < 8; ++ct) {
      bool any = (c == 0) ? (ct >= w * 2) : (c == 2) ? (ct <= w * 2 + 1) : true;
      if (any) {
        short8 kf0 = *(const short8*)(&kt[ct * 16 + l16][quad * 8]);
        short8 kf1 = *(const short8*)(&kt[ct * 16 + l16][32 + quad * 8]);
#pragma unroll
        for (int rt = 0; rt < 2; ++rt) {
          bool valid = (c == 0) ? (ct >= w * 2 + rt) : (c == 2) ? (ct <= w * 2 + rt) : true;
          if (valid) {
            s[rt][ct] = MFMA_B16(qf[rt][0], kf0, s[rt][ct]);
            s[rt][ct] = MFMA_B16(qf[rt][1], kf1, s[rt][ct]);
          }
        }
      }
    }

    // P = exp2(S); per-element mask only on the diagonal tile; zero-fill
    // fully-masked tiles whose enclosing 32-key ks-tile is still live.
#pragma unroll
    for (int rt = 0; rt < 2; ++rt) {
      int wrt = w * 2 + rt;
#pragma unroll
      for (int ct = 0; ct < 8; ++ct) {
        bool tileMasked = (c == 0) ? (ct < wrt) : (c == 2) ? (ct > wrt) : false;
        bool ksDead = (c == 0) ? (2 * (ct >> 1) + 1 < wrt)
                    : (c == 2) ? (2 * (ct >> 1) > wrt) : false;
        bool diag = (c != 1) && (ct == wrt);
        if (ksDead) continue;
        if (tileMasked) {
#pragma unroll
          for (int rg = 0; rg < 4; ++rg)
            pl[w][rt * 16 + quad * 4 + rg][ct * 16 + l16] = 0;
        } else if (diag) {
#pragma unroll
          for (int rg = 0; rg < 4; ++rg) {
            int r16 = quad * 4 + rg;      // row within diag tile
            float p = exp2f(s[rt][ct][rg]);
            if (c == 0) p = (l16 < r16) ? 0.f : p;
            else        p = (l16 > r16) ? 0.f : p;
            pl[w][rt * 16 + r16][ct * 16 + l16] = f2bf_rtz(p);
          }
        } else {
#pragma unroll
          for (int rg = 0; rg < 4; ++rg)
            pl[w][rt * 16 + quad * 4 + rg][ct * 16 + l16] = f2bf_rtz(exp2f(s[rt][ct][rg]));
        }
      }
    }

    __syncthreads();   // order P-stores before cross-lane P-loads

    // O += P V ; row sums via ones-fragment; skip dead ks-tiles
#pragma unroll
    for (int ks = 0; ks < 4; ++ks) {
      bool anyrt = (c == 0) ? (2 * ks + 1 >= w * 2) : (c == 2) ? (2 * ks <= w * 2 + 1) : true;
      if (!anyrt) continue;
      short8 vf[4];
#pragma unroll
      for (int ct = 0; ct < 4; ++ct)
        vf[ct] = *(const short8*)(&vt[ct * 16 + l16][ks * 32 + quad * 8]);
#pragma unroll
      for (int rt = 0; rt < 2; ++rt) {
        int wrt = w * 2 + rt;
        bool ksDead = (c == 0) ? (2 * ks + 1 < wrt) : (c == 2) ? (2 * ks > wrt) : false;
        if (ksDead) continue;
        short8 pf = *(const short8*)(&pl[w][rt * 16 + l16][ks * 32 + quad * 8]);
#pragma unroll
        for (int ct = 0; ct < 4; ++ct) o[rt][ct] = MFMA_B16(pf, vf[ct], o[rt][ct]);
        osum[rt] = MFMA_B16(pf, onesf, osum[rt]);
      }
    }
  }

  // normalize + store to (B, L, C) bf16; sum lives in col 0 of the ones tile
#pragma unroll
  for (int rt = 0; rt < 2; ++rt) {
#pragma unroll
    for (int rg = 0; rg < 4; ++rg) {
      float ssum = __shfl(osum[rt][rg], lane & 48);
      float inv = 1.f / ssum;
      int r = n * 128 + w * 32 + rt * 16 + quad * 4 + rg;
#pragma unroll
      for (int ct = 0; ct < 4; ++ct)
        attnb[(size_t)(b * L + r) * 1024 + h * 64 + ct * 16 + l16] =
            f2bf(o[rt][ct][rg] * inv);
    }
  }
}

// ---------------- output projection GEMM (fp32 out), 256x128 8-phase-style ----------------
__global__ __launch_bounds__(512, 2) void gemm_out(
    const short* __restrict__ attnb, const short* __restrict__ wTo,
    const float* __restrict__ bo, float* __restrict__ outp) {
  __shared__ __align__(16) short As[2 * 16384];
  __shared__ __align__(16) short Bs[2 * 8192];
  int m0 = blockIdx.x * 256, n0 = blockIdx.y * 128;

  floatx4 acc[8][2];
  gemm_core_256x128(attnb + (size_t)m0 * 1024, wTo + (size_t)n0 * 1024, As, Bs, acc);

  int tid = threadIdx.x, w = tid >> 6, lane = tid & 63, quad = lane >> 4, l16 = lane & 15;
  int wm = w >> 2, wn = w & 3;
#pragma unroll
  for (int mf = 0; mf < 8; ++mf)
#pragma unroll
    for (int nf = 0; nf < 2; ++nf)
#pragma unroll
      for (int rg = 0; rg < 4; ++rg) {
        int m = m0 + wm * 128 + mf * 16 + quad * 4 + rg;
        int cc = n0 + wn * 32 + nf * 16 + l16;
        outp[(size_t)m * 1024 + cc] = acc[mf][nf][rg] + bo[cc];
      }
}

extern "C" void kernel_launch(void* const* d_in, const int* in_sizes, int n_in,
                              void* d_out, int out_size, void* d_ws, size_t ws_size,
                              hipStream_t stream) {
  const float* x  = (const float*)d_in[0];
  const float* wq = (const float*)d_in[1];
  const float* bq = (const float*)d_in[2];
  const float* wk = (const float*)d_in[3];
  const float* bk = (const float*)d_in[4];
  const float* wv = (const float*)d_in[5];
  const float* bv = (const float*)d_in[6];
  const float* wo = (const float*)d_in[7];
  const float* bo = (const float*)d_in[8];

  char* ws = (char*)d_ws;
  short* xb    = (short*)ws;                   // [0,16M): x bf16
  short* wT    = (short*)(ws + (16u << 20));   // [16M,24M): 4x W^T bf16
  short* qkv   = (short*)(ws + (24u << 20));   // [24M,72M): Q,K,V in (B,H,L,D)
  short* attnb = (short*)(ws + (72u << 20));   // [72M,88M): attention out (B,L,C) bf16

  prep<<<12288, 256, 0, stream>>>((const float4*)x, (short4v*)xb, wq, wk, wv, wo, wT);
  gemm_qkv<<<dim3(32, 8, 3), 512, 0, stream>>>(xb, wT, bq, bk, bv, qkv);
  attn_kern<<<dim3(32, 16, 2), 256, 0, stream>>>(qkv, attnb);
  gemm_out<<<dim3(32, 8), 512, 0, stream>>>(attnb, wT + 3u * 1024 * 1024, bo, (float*)d_out);
}